// Round 1
// baseline (1144.287 us; speedup 1.0000x reference)
//
#include <hip/hip_runtime.h>
#include <stdint.h>

// GatedMoE: B=4,N=2048,D=1024,F=4096,E=8,K=2 (top-2 sparse; dense ref only consumes top-2)
// Pipeline: gate(f64 logits)->route->bf16 convert/transpose->grouped GEMM1(relu)->grouped GEMM2->atomic combine
// ws usage ~274 MB.

#define E_ 8
#define D_ 1024
#define F_ 4096
#define NTOK 8192

typedef __bf16 bf16x8 __attribute__((ext_vector_type(8)));
typedef float f32x4 __attribute__((ext_vector_type(4)));
typedef unsigned short ushort_t;

__device__ __forceinline__ ushort_t f2bf(float f) {
  union { float f; unsigned u; } v; v.f = f;
  unsigned r = v.u + 0x7fff + ((v.u >> 16) & 1);   // RNE
  return (ushort_t)(r >> 16);
}

__device__ __forceinline__ void gload16(const void* g, void* l) {
  __builtin_amdgcn_global_load_lds((__attribute__((address_space(1))) void*)(g),
                                   (__attribute__((address_space(3))) void*)(l),
                                   16, 0, 0);
}

// ---------------- gating: one wave per token, f64 accumulation ----------------
__global__ __launch_bounds__(256) void gate_k(const float* __restrict__ x,
    const float* __restrict__ Wg, const float* __restrict__ bg,
    int* counts, int* tk_idx, float* tk_score) {
  __shared__ float wg[D_ * E_];
  for (int i = threadIdx.x; i < D_ * E_; i += 256) wg[i] = Wg[i];
  __syncthreads();
  const int lane = threadIdx.x & 63;
  const int wv = threadIdx.x >> 6;
  const int t = blockIdx.x * 4 + wv;
  const float* xr = x + (size_t)t * D_;
  double acc[E_];
#pragma unroll
  for (int e = 0; e < E_; ++e) acc[e] = 0.0;
  for (int i = 0; i < D_ / 64; ++i) {
    const int d = i * 64 + lane;
    const double xv = (double)xr[d];
#pragma unroll
    for (int e = 0; e < E_; ++e) acc[e] += xv * (double)wg[d * E_ + e];
  }
#pragma unroll
  for (int e = 0; e < E_; ++e) {
    double v = acc[e];
#pragma unroll
    for (int s = 32; s > 0; s >>= 1) v += __shfl_xor(v, s, 64);
    acc[e] = v;
  }
  if (lane == 0) {
    double l[E_], m = -1e300;
#pragma unroll
    for (int e = 0; e < E_; ++e) { l[e] = acc[e] + (double)bg[e]; m = (l[e] > m) ? l[e] : m; }
    double p[E_], s = 0.0;
#pragma unroll
    for (int e = 0; e < E_; ++e) { p[e] = exp(l[e] - m); s += p[e]; }
    int i1 = 0;
#pragma unroll
    for (int e = 1; e < E_; ++e) if (p[e] > p[i1]) i1 = e;      // ties -> lowest idx
    int i2 = -1;
#pragma unroll
    for (int e = 0; e < E_; ++e) if (e != i1 && (i2 < 0 || p[e] > p[i2])) i2 = e;
    tk_idx[2 * t] = i1; tk_idx[2 * t + 1] = i2;
    tk_score[2 * t] = (float)(p[i1] / s);
    tk_score[2 * t + 1] = (float)(p[i2] / s);
    atomicAdd(&counts[i1], 1);
    atomicAdd(&counts[i2], 1);
  }
}

__global__ void offsets_k(const int* __restrict__ counts, int* __restrict__ offsets) {
  if (threadIdx.x == 0) {
    int s = 0;
    for (int e = 0; e < E_; ++e) { offsets[e] = s; s += counts[e]; }
    offsets[E_] = s;
  }
}

__global__ __launch_bounds__(256) void assign_k(const int* __restrict__ tk_idx,
    const float* __restrict__ tk_score, const int* __restrict__ offsets,
    int* counts2, int* slot_token, float* slot_scale) {
  const int t = blockIdx.x * 256 + threadIdx.x;
#pragma unroll
  for (int k = 0; k < 2; ++k) {
    const int e = tk_idx[2 * t + k];
    const int pos = atomicAdd(&counts2[e], 1);
    const int slot = offsets[e] + pos;
    slot_token[slot] = t;
    slot_scale[slot] = tk_score[2 * t + k];
  }
}

// ---------------- f32 -> bf16 convert (x) ----------------
__global__ __launch_bounds__(256) void convert_x_k(const float* __restrict__ x,
                                                   ushort_t* __restrict__ xb) {
  const size_t i = ((size_t)blockIdx.x * 256 + threadIdx.x) * 8;
  const float4 a = *(const float4*)(x + i);
  const float4 b = *(const float4*)(x + i + 4);
  union { ushort_t u[8]; uint4 v; } p;
  p.u[0] = f2bf(a.x); p.u[1] = f2bf(a.y); p.u[2] = f2bf(a.z); p.u[3] = f2bf(a.w);
  p.u[4] = f2bf(b.x); p.u[5] = f2bf(b.y); p.u[6] = f2bf(b.z); p.u[7] = f2bf(b.w);
  *(uint4*)(xb + i) = p.v;
}

// ---------------- f32 [E][R][C] -> bf16 [E][C][R] transpose ----------------
__global__ __launch_bounds__(256) void transpose_conv(const float* __restrict__ in,
    ushort_t* __restrict__ out, int R, int C) {
  __shared__ float t[32][33];
  const int ex = blockIdx.z;
  const int r0 = blockIdx.y * 32, c0 = blockIdx.x * 32;
  const float* ein = in + (size_t)ex * R * C;
  ushort_t* eout = out + (size_t)ex * R * C;
  const int tx = threadIdx.x & 31, ty = threadIdx.x >> 5;
#pragma unroll
  for (int j = 0; j < 32; j += 8)
    t[ty + j][tx] = ein[(size_t)(r0 + ty + j) * C + (c0 + tx)];
  __syncthreads();
#pragma unroll
  for (int j = 0; j < 32; j += 8)
    eout[(size_t)(c0 + ty + j) * R + (r0 + tx)] = f2bf(t[tx][ty + j]);
}

// ---------------- grouped GEMM, m97 structure: 128x128 tile, BK=32, 4 waves ----------------
// MODE 0: A = xb rows gathered by slot_token; out = relu(acc + b1) -> H (bf16)
// MODE 1: A = h rows (contiguous slots);      out = atomicAdd(Out[token], scale*(acc + b2))
template <int MODE>
__global__ __launch_bounds__(256) void moe_gemm(
    const ushort_t* __restrict__ A, const ushort_t* __restrict__ Bt,
    const float* __restrict__ bias,
    const int* __restrict__ offs, const int* __restrict__ counts,
    const int* __restrict__ slot_token, const float* __restrict__ slot_scale,
    ushort_t* __restrict__ H, float* __restrict__ Out, int N, int K) {
  const int e = blockIdx.z;
  const int cnt = counts[e];
  const int mb = blockIdx.y;
  if (mb * 128 >= cnt) return;
  const int off = offs[e];
  const int n0 = blockIdx.x * 128;

  __shared__ ushort_t As[128 * 32];
  __shared__ ushort_t Bs[128 * 32];

  const int lane = threadIdx.x & 63, wv = threadIdx.x >> 6;
  const int wm = wv >> 1, wn = wv & 1;
  const int sub = lane >> 2, quad = lane & 3;

  // staging source pointers (2 A-rows + 2 B-rows per thread, fixed across K)
  const ushort_t* ag[2];
  const ushort_t* bgp[2];
#pragma unroll
  for (int j = 0; j < 2; ++j) {
    const int row = j * 64 + wv * 16 + sub;
    int gm = mb * 128 + row;
    if (gm >= cnt) gm = cnt - 1;  // clamp; stores are guarded
    size_t arow;
    if (MODE == 0) arow = (size_t)slot_token[off + gm] * (size_t)K;
    else           arow = (size_t)(off + gm) * (size_t)K;
    ag[j] = A + arow + quad * 8;
    bgp[j] = Bt + ((size_t)e * N + (size_t)(n0 + row)) * (size_t)K + quad * 8;
  }
  ushort_t* al[2] = { As + (wv * 16) * 32, As + (64 + wv * 16) * 32 };
  ushort_t* bl[2] = { Bs + (wv * 16) * 32, Bs + (64 + wv * 16) * 32 };

  f32x4 acc[4][4];
#pragma unroll
  for (int i = 0; i < 4; ++i)
#pragma unroll
    for (int j = 0; j < 4; ++j) { acc[i][j][0] = 0.f; acc[i][j][1] = 0.f; acc[i][j][2] = 0.f; acc[i][j][3] = 0.f; }

  const int fr = lane & 15, kg = lane >> 4;
  const int nk = K / 32;
  for (int kt = 0; kt < nk; ++kt) {
    const int ko = kt * 32;
    gload16(ag[0] + ko, al[0]);
    gload16(ag[1] + ko, al[1]);
    gload16(bgp[0] + ko, bl[0]);
    gload16(bgp[1] + ko, bl[1]);
    __syncthreads();  // compiler drains vmcnt before barrier
    bf16x8 a[4], b[4];
#pragma unroll
    for (int i = 0; i < 4; ++i)
      a[i] = *(const bf16x8*)(As + (wm * 64 + i * 16 + fr) * 32 + kg * 8);
#pragma unroll
    for (int j = 0; j < 4; ++j)
      b[j] = *(const bf16x8*)(Bs + (wn * 64 + j * 16 + fr) * 32 + kg * 8);
#pragma unroll
    for (int i = 0; i < 4; ++i)
#pragma unroll
      for (int j = 0; j < 4; ++j)
        acc[i][j] = __builtin_amdgcn_mfma_f32_16x16x32_bf16(a[i], b[j], acc[i][j], 0, 0, 0);
    __syncthreads();
  }

  // epilogue: C/D layout col=lane&15, row=(lane>>4)*4+reg
  const int rg = lane >> 4;
#pragma unroll
  for (int i = 0; i < 4; ++i) {
#pragma unroll
    for (int q = 0; q < 4; ++q) {
      const int m = wm * 64 + i * 16 + rg * 4 + q;
      const int gm = mb * 128 + m;
      if (gm < cnt) {
        if (MODE == 0) {
          ushort_t* hr = H + (size_t)(off + gm) * (size_t)N + n0;
#pragma unroll
          for (int j = 0; j < 4; ++j) {
            const int n = wn * 64 + j * 16 + fr;
            float v = acc[i][j][q] + bias[(size_t)e * N + n0 + n];
            hr[n] = f2bf(v > 0.f ? v : 0.f);
          }
        } else {
          const int slot = off + gm;
          const int tok = slot_token[slot];
          const float sc = slot_scale[slot];
          float* orow = Out + (size_t)tok * D_ + n0;
#pragma unroll
          for (int j = 0; j < 4; ++j) {
            const int n = wn * 64 + j * 16 + fr;
            float v = acc[i][j][q] + bias[(size_t)e * N + n0 + n];
            atomicAdd(orow + n, sc * v);
          }
        }
      }
    }
  }
}

extern "C" void kernel_launch(void* const* d_in, const int* in_sizes, int n_in,
                              void* d_out, int out_size, void* d_ws, size_t ws_size,
                              hipStream_t stream) {
  const float* x  = (const float*)d_in[0];
  const float* Wg = (const float*)d_in[1];
  const float* bg = (const float*)d_in[2];
  const float* W1 = (const float*)d_in[3];
  const float* b1 = (const float*)d_in[4];
  const float* W2 = (const float*)d_in[5];
  const float* b2 = (const float*)d_in[6];
  float* out = (float*)d_out;
  char* ws = (char*)d_ws;

  int*   counts     = (int*)(ws + 0);
  int*   counts2    = (int*)(ws + 64);
  int*   offsets    = (int*)(ws + 128);
  int*   tk_idx     = (int*)(ws + 256);
  float* tk_score   = (float*)(ws + 256 + 65536);
  int*   slot_token = (int*)(ws + 256 + 2 * 65536);
  float* slot_scale = (float*)(ws + 256 + 3 * 65536);

  ushort_t* xb  = (ushort_t*)(ws + (1 << 20));
  ushort_t* w1t = xb + (size_t)NTOK * D_;            // [E][F][D] bf16
  ushort_t* w2t = w1t + (size_t)E_ * F_ * D_;        // [E][D][F] bf16
  ushort_t* h   = w2t + (size_t)E_ * D_ * F_;        // [2*NTOK][F] bf16

  hipMemsetAsync(ws, 0, 256, stream);                         // counts/counts2/offsets
  hipMemsetAsync(d_out, 0, sizeof(float) * (size_t)out_size, stream);

  convert_x_k<<<(NTOK * D_) / (256 * 8), 256, 0, stream>>>(x, xb);
  transpose_conv<<<dim3(F_ / 32, D_ / 32, E_), 256, 0, stream>>>(W1, w1t, D_, F_);
  transpose_conv<<<dim3(D_ / 32, F_ / 32, E_), 256, 0, stream>>>(W2, w2t, F_, D_);
  gate_k<<<NTOK / 4, 256, 0, stream>>>(x, Wg, bg, counts, tk_idx, tk_score);
  offsets_k<<<1, 64, 0, stream>>>(counts, offsets);
  assign_k<<<NTOK / 256, 256, 0, stream>>>(tk_idx, tk_score, offsets, counts2, slot_token, slot_scale);

  moe_gemm<0><<<dim3(F_ / 128, NTOK / 128, E_), 256, 0, stream>>>(
      xb, w1t, b1, offsets, counts, slot_token, slot_scale, h, nullptr, F_, D_);
  moe_gemm<1><<<dim3(D_ / 128, NTOK / 128, E_), 256, 0, stream>>>(
      h, w2t, b2, offsets, counts, slot_token, slot_scale, nullptr, out, D_, F_);
}

// Round 2
// 1082.381 us; speedup vs baseline: 1.0572x; 1.0572x over previous
//
#include <hip/hip_runtime.h>
#include <stdint.h>

// GatedMoE: B=4,N=2048,D=1024,F=4096,E=8,K=2 (top-2 sparse)
// R2: 256x256/BK=64 8-wave double-buffered prefetch GEMM (T3-minimum 2-phase),
//     XOR-swizzled LDS (pre-swizzled global source, rule #21), faster transposes,
//     conflict-free gate LDS layout.

#define E_ 8
#define D_ 1024
#define F_ 4096
#define NTOK 8192

typedef __bf16 bf16x8 __attribute__((ext_vector_type(8)));
typedef float f32x4 __attribute__((ext_vector_type(4)));
typedef unsigned short ushort_t;

__device__ __forceinline__ ushort_t f2bf(float f) {
  union { float f; unsigned u; } v; v.f = f;
  unsigned r = v.u + 0x7fff + ((v.u >> 16) & 1);   // RNE
  return (ushort_t)(r >> 16);
}

__device__ __forceinline__ void gload16(const void* g, void* l) {
  __builtin_amdgcn_global_load_lds((__attribute__((address_space(1))) void*)(g),
                                   (__attribute__((address_space(3))) void*)(l),
                                   16, 0, 0);
}

// ---------------- gating: one wave per token, f64 accumulation ----------------
__global__ __launch_bounds__(256) void gate_k(const float* __restrict__ x,
    const float* __restrict__ Wg, const float* __restrict__ bg,
    int* counts, int* tk_idx, float* tk_score) {
  __shared__ float wg[E_ * D_];                      // transposed [E][D]: conflict-free reads
  for (int i = threadIdx.x; i < D_ * E_; i += 256) wg[(i & 7) * D_ + (i >> 3)] = Wg[i];
  __syncthreads();
  const int lane = threadIdx.x & 63;
  const int wv = threadIdx.x >> 6;
  const int t = blockIdx.x * 4 + wv;
  const float* xr = x + (size_t)t * D_;
  double acc[E_];
#pragma unroll
  for (int e = 0; e < E_; ++e) acc[e] = 0.0;
  for (int i = 0; i < D_ / 64; ++i) {
    const int d = i * 64 + lane;
    const double xv = (double)xr[d];
#pragma unroll
    for (int e = 0; e < E_; ++e) acc[e] += xv * (double)wg[e * D_ + d];
  }
#pragma unroll
  for (int e = 0; e < E_; ++e) {
    double v = acc[e];
#pragma unroll
    for (int s = 32; s > 0; s >>= 1) v += __shfl_xor(v, s, 64);
    acc[e] = v;
  }
  if (lane == 0) {
    double l[E_], m = -1e300;
#pragma unroll
    for (int e = 0; e < E_; ++e) { l[e] = acc[e] + (double)bg[e]; m = (l[e] > m) ? l[e] : m; }
    double p[E_], s = 0.0;
#pragma unroll
    for (int e = 0; e < E_; ++e) { p[e] = exp(l[e] - m); s += p[e]; }
    int i1 = 0;
#pragma unroll
    for (int e = 1; e < E_; ++e) if (p[e] > p[i1]) i1 = e;
    int i2 = -1;
#pragma unroll
    for (int e = 0; e < E_; ++e) if (e != i1 && (i2 < 0 || p[e] > p[i2])) i2 = e;
    tk_idx[2 * t] = i1; tk_idx[2 * t + 1] = i2;
    tk_score[2 * t] = (float)(p[i1] / s);
    tk_score[2 * t + 1] = (float)(p[i2] / s);
    atomicAdd(&counts[i1], 1);
    atomicAdd(&counts[i2], 1);
  }
}

__global__ void offsets_k(const int* __restrict__ counts, int* __restrict__ offsets) {
  if (threadIdx.x == 0) {
    int s = 0;
    for (int e = 0; e < E_; ++e) { offsets[e] = s; s += counts[e]; }
    offsets[E_] = s;
  }
}

__global__ __launch_bounds__(256) void assign_k(const int* __restrict__ tk_idx,
    const float* __restrict__ tk_score, const int* __restrict__ offsets,
    int* counts2, int* slot_token, float* slot_scale) {
  const int t = blockIdx.x * 256 + threadIdx.x;
#pragma unroll
  for (int k = 0; k < 2; ++k) {
    const int e = tk_idx[2 * t + k];
    const int pos = atomicAdd(&counts2[e], 1);
    const int slot = offsets[e] + pos;
    slot_token[slot] = t;
    slot_scale[slot] = tk_score[2 * t + k];
  }
}

// ---------------- f32 -> bf16 convert (x) ----------------
__global__ __launch_bounds__(256) void convert_x_k(const float* __restrict__ x,
                                                   ushort_t* __restrict__ xb) {
  const size_t i = ((size_t)blockIdx.x * 256 + threadIdx.x) * 8;
  const float4 a = *(const float4*)(x + i);
  const float4 b = *(const float4*)(x + i + 4);
  union { ushort_t u[8]; uint4 v; } p;
  p.u[0] = f2bf(a.x); p.u[1] = f2bf(a.y); p.u[2] = f2bf(a.z); p.u[3] = f2bf(a.w);
  p.u[4] = f2bf(b.x); p.u[5] = f2bf(b.y); p.u[6] = f2bf(b.z); p.u[7] = f2bf(b.w);
  *(uint4*)(xb + i) = p.v;
}

// ---------------- f32 [E][R][C] -> bf16 [E][C][R], 64x64 tiles ----------------
__global__ __launch_bounds__(256) void transpose_conv(const float* __restrict__ in,
    ushort_t* __restrict__ out, int R, int C) {
  __shared__ float t[64][65];
  const int ex = blockIdx.z;
  const int c0 = blockIdx.x * 64, r0 = blockIdx.y * 64;
  const float* ein = in + (size_t)ex * R * C;
  ushort_t* eout = out + (size_t)ex * R * C;
  const int tid = threadIdx.x;
#pragma unroll
  for (int it = 0; it < 4; ++it) {
    const int idx = it * 256 + tid;
    const int r = idx >> 4, cv = (idx & 15) * 4;
    const float4 v = *(const float4*)(ein + (size_t)(r0 + r) * C + c0 + cv);
    t[cv + 0][r] = v.x; t[cv + 1][r] = v.y; t[cv + 2][r] = v.z; t[cv + 3][r] = v.w;
  }
  __syncthreads();
#pragma unroll
  for (int it = 0; it < 2; ++it) {
    const int idx = it * 256 + tid;
    const int c = idx >> 3, sg = (idx & 7) * 8;
    union { ushort_t u[8]; uint4 v; } p;
#pragma unroll
    for (int k = 0; k < 8; ++k) p.u[k] = f2bf(t[c][sg + k]);
    *(uint4*)(eout + (size_t)(c0 + c) * R + r0 + sg) = p.v;
  }
}

// ---------------- grouped GEMM: 256x256 tile, BK=64, 8 waves, 2-phase dbuf ----------------
// LDS per buffer: A 256x64 bf16 (32KB) + B 256x64 (32KB); double-buffered = 128KB.
// Read-side XOR swizzle byte^=((row&7)<<4) with pre-swizzled global source (linear gload_lds dest).
// MODE 0: A rows gathered via slot_token; out = relu(acc+b1) -> H bf16
// MODE 1: A = h rows (contiguous);         out = atomicAdd(Out[token], scale*(acc+b2))
template <int MODE>
__global__ __launch_bounds__(512, 2) void moe_gemm(
    const ushort_t* __restrict__ A, const ushort_t* __restrict__ Bt,
    const float* __restrict__ bias,
    const int* __restrict__ offs, const int* __restrict__ counts,
    const int* __restrict__ slot_token, const float* __restrict__ slot_scale,
    ushort_t* __restrict__ H, float* __restrict__ Out, int N, int K) {
  const int e = blockIdx.z;
  const int cnt = counts[e];
  const int mb = blockIdx.y;
  if (mb * 256 >= cnt) return;
  const int off = offs[e];
  const int n0 = blockIdx.x * 256;

  extern __shared__ char smem[];  // 131072 bytes

  const int tid = threadIdx.x;
  const int w = tid >> 6, l = tid & 63;
  const int wm = w >> 2, wn = w & 3;

  // ---- staging sources: 4 A-rows + 4 B-rows per thread (chunk = 8 rows = 1KB) ----
  const int lr = l >> 3;                       // row within chunk (== row&7)
  const int swk = ((l & 7) * 16) ^ (lr << 4);  // pre-swizzled k-byte in source
  const char* asrc[4];
  const char* bsrc[4];
#pragma unroll
  for (int q = 0; q < 4; ++q) {
    const int row = (w * 4 + q) * 8 + lr;
    int gm = mb * 256 + row;
    if (gm >= cnt) gm = cnt - 1;
    size_t arow;
    if (MODE == 0) arow = (size_t)slot_token[off + gm];
    else           arow = (size_t)(off + gm);
    asrc[q] = (const char*)A + arow * (size_t)K * 2 + swk;
    bsrc[q] = (const char*)Bt + ((size_t)e * N + (size_t)(n0 + row)) * (size_t)K * 2 + swk;
  }

  // ---- fragment read bases (swizzled) ----
  const int fr = l & 15, kg = l >> 4, rg = kg;
  const int sw = (fr & 7) << 4;
  const int baseA0 = (wm * 128 + fr) * 128 + ((kg * 16) ^ sw);
  const int baseA1 = (wm * 128 + fr) * 128 + ((64 + kg * 16) ^ sw);
  const int baseB0 = 32768 + (wn * 64 + fr) * 128 + ((kg * 16) ^ sw);
  const int baseB1 = 32768 + (wn * 64 + fr) * 128 + ((64 + kg * 16) ^ sw);

  f32x4 acc[8][4];
#pragma unroll
  for (int i = 0; i < 8; ++i)
#pragma unroll
    for (int j = 0; j < 4; ++j) { acc[i][j][0] = 0.f; acc[i][j][1] = 0.f; acc[i][j][2] = 0.f; acc[i][j][3] = 0.f; }

  const int nk = K / 64;
  int curOff = 0;

#define STAGE(KOFF, LOFF)                                                     \
  do {                                                                        \
    _Pragma("unroll")                                                         \
    for (int q = 0; q < 4; ++q)                                               \
      gload16(asrc[q] + (KOFF), smem + (LOFF) + (w * 4 + q) * 1024);          \
    _Pragma("unroll")                                                         \
    for (int q = 0; q < 4; ++q)                                               \
      gload16(bsrc[q] + (KOFF), smem + (LOFF) + 32768 + (w * 4 + q) * 1024);  \
  } while (0)

  STAGE(0, 0);
  __syncthreads();

  for (int kt = 0; kt < nk; ++kt) {
    if (kt + 1 < nk) STAGE((kt + 1) * 128, curOff ^ 65536);
#pragma unroll
    for (int s = 0; s < 2; ++s) {
      bf16x8 a[8], b[4];
      const int bA = curOff + (s ? baseA1 : baseA0);
      const int bB = curOff + (s ? baseB1 : baseB0);
#pragma unroll
      for (int i = 0; i < 8; ++i) a[i] = *(const bf16x8*)(smem + bA + i * 2048);
#pragma unroll
      for (int j = 0; j < 4; ++j) b[j] = *(const bf16x8*)(smem + bB + j * 2048);
#pragma unroll
      for (int i = 0; i < 8; ++i)
#pragma unroll
        for (int j = 0; j < 4; ++j)
          acc[i][j] = __builtin_amdgcn_mfma_f32_16x16x32_bf16(a[i], b[j], acc[i][j], 0, 0, 0);
    }
    __syncthreads();
    curOff ^= 65536;
  }
#undef STAGE

  // ---- epilogue: C/D layout col=lane&15, row=(lane>>4)*4+reg ----
  const float* bias_e = bias + (size_t)e * N + n0;
#pragma unroll
  for (int i = 0; i < 8; ++i) {
#pragma unroll
    for (int q = 0; q < 4; ++q) {
      const int m = wm * 128 + i * 16 + rg * 4 + q;
      const int gm = mb * 256 + m;
      if (gm < cnt) {
        if (MODE == 0) {
          ushort_t* hr = H + (size_t)(off + gm) * (size_t)N + n0;
#pragma unroll
          for (int j = 0; j < 4; ++j) {
            const int n = wn * 64 + j * 16 + fr;
            float v = acc[i][j][q] + bias_e[n];
            hr[n] = f2bf(v > 0.f ? v : 0.f);
          }
        } else {
          const int slot = off + gm;
          const int tok = slot_token[slot];
          const float sc = slot_scale[slot];
          float* orow = Out + (size_t)tok * D_ + n0;
#pragma unroll
          for (int j = 0; j < 4; ++j) {
            const int n = wn * 64 + j * 16 + fr;
            float v = acc[i][j][q] + bias_e[n];
            atomicAdd(orow + n, sc * v);
          }
        }
      }
    }
  }
}

extern "C" void kernel_launch(void* const* d_in, const int* in_sizes, int n_in,
                              void* d_out, int out_size, void* d_ws, size_t ws_size,
                              hipStream_t stream) {
  const float* x  = (const float*)d_in[0];
  const float* Wg = (const float*)d_in[1];
  const float* bg = (const float*)d_in[2];
  const float* W1 = (const float*)d_in[3];
  const float* b1 = (const float*)d_in[4];
  const float* W2 = (const float*)d_in[5];
  const float* b2 = (const float*)d_in[6];
  float* out = (float*)d_out;
  char* ws = (char*)d_ws;

  int*   counts     = (int*)(ws + 0);
  int*   counts2    = (int*)(ws + 64);
  int*   offsets    = (int*)(ws + 128);
  int*   tk_idx     = (int*)(ws + 256);
  float* tk_score   = (float*)(ws + 256 + 65536);
  int*   slot_token = (int*)(ws + 256 + 2 * 65536);
  float* slot_scale = (float*)(ws + 256 + 3 * 65536);

  ushort_t* xb  = (ushort_t*)(ws + (1 << 20));
  ushort_t* w1t = xb + (size_t)NTOK * D_;            // [E][F][D] bf16
  ushort_t* w2t = w1t + (size_t)E_ * F_ * D_;        // [E][D][F] bf16
  ushort_t* h   = w2t + (size_t)E_ * D_ * F_;        // [2*NTOK][F] bf16

  // allow 128KB dynamic LDS (ignore error if already set / unsupported)
  (void)hipFuncSetAttribute((const void*)moe_gemm<0>,
                            hipFuncAttributeMaxDynamicSharedMemorySize, 131072);
  (void)hipFuncSetAttribute((const void*)moe_gemm<1>,
                            hipFuncAttributeMaxDynamicSharedMemorySize, 131072);

  hipMemsetAsync(ws, 0, 256, stream);
  hipMemsetAsync(d_out, 0, sizeof(float) * (size_t)out_size, stream);

  convert_x_k<<<(NTOK * D_) / (256 * 8), 256, 0, stream>>>(x, xb);
  transpose_conv<<<dim3(F_ / 64, D_ / 64, E_), 256, 0, stream>>>(W1, w1t, D_, F_);
  transpose_conv<<<dim3(D_ / 64, F_ / 64, E_), 256, 0, stream>>>(W2, w2t, F_, D_);
  gate_k<<<NTOK / 4, 256, 0, stream>>>(x, Wg, bg, counts, tk_idx, tk_score);
  offsets_k<<<1, 64, 0, stream>>>(counts, offsets);
  assign_k<<<NTOK / 256, 256, 0, stream>>>(tk_idx, tk_score, offsets, counts2, slot_token, slot_scale);

  moe_gemm<0><<<dim3(F_ / 256, 64, E_), 512, 131072, stream>>>(
      xb, w1t, b1, offsets, counts, slot_token, slot_scale, h, nullptr, F_, D_);
  moe_gemm<1><<<dim3(D_ / 256, 64, E_), 512, 131072, stream>>>(
      h, w2t, b2, offsets, counts, slot_token, slot_scale, nullptr, out, D_, F_);
}